// Round 5
// baseline (1831.803 us; speedup 1.0000x reference)
//
#include <hip/hip_runtime.h>

#define NS 8
#define ML 4096
#define HD 1024
#define K2 2048
#define NEV 32768
#define NLEV 12
#define NE 16384
#define NSLOT (NS * ML)
#define CAP 8
#define BK 32
#define NT (K2 / BK)          // 64 K-tiles
#define TILE_ELEMS 12288      // A 256x32 (8192) + B 128x32 (4096) bf16
#define LDS_BYTES 73728       // 3 buffers x 24 KB -> 2 blocks/CU (144 KB of 160)

typedef __attribute__((ext_vector_type(8))) short bf16x8;
typedef __attribute__((ext_vector_type(4))) float f32x4;

typedef __attribute__((address_space(1))) const void cvoid_g;
typedef __attribute__((address_space(3))) void void_l;

static __device__ __forceinline__ void load_lds_16(const void* g, void* l) {
    __builtin_amdgcn_global_load_lds((cvoid_g*)g, (void_l*)l, 16, 0, 0);
}

static __device__ __forceinline__ unsigned short f2bf(float f) {
    unsigned u = __float_as_uint(f);
    unsigned r = (u + 0x7fffu + ((u >> 16) & 1u)) >> 16;
    return (unsigned short)r;
}

static __device__ __forceinline__ float fast_tanh(float x) {
    return 1.0f - 2.0f / (__expf(2.0f * x) + 1.0f);
}

// ---- W [2048][1024] f32 -> WbT [1024][2048] bf16 (transposed) ----
__global__ void wt_kernel(const float* __restrict__ W, unsigned short* __restrict__ WbT) {
    __shared__ unsigned short tile[64][65];
    const int t = threadIdx.x;
    const int k0 = blockIdx.x * 64;
    const int n0 = blockIdx.y * 64;
#pragma unroll
    for (int i = 0; i < 16; i++) {
        int idx = i * 256 + t;
        int r = idx >> 6, c = idx & 63;
        tile[r][c] = f2bf(W[(size_t)(k0 + r) * HD + n0 + c]);
    }
    __syncthreads();
#pragma unroll
    for (int i = 0; i < 16; i++) {
        int idx = i * 256 + t;
        int r = idx >> 6, c = idx & 63;
        WbT[(size_t)(n0 + r) * K2 + k0 + c] = tile[c][r];
    }
}

// ---- char dedupe pass 1 ----
__global__ void char_ticket(const int* __restrict__ cseq, const int* __restrict__ cpos,
                            int* __restrict__ counts, int* __restrict__ ticket,
                            int* __restrict__ evlist) {
    const int e = blockIdx.x * 256 + threadIdx.x;
    if (e >= NEV) return;
    const int slot = cseq[e] * ML + cpos[e];
    const int t = atomicAdd(&counts[slot], 1);
    ticket[e] = t;
    if (t < CAP) evlist[slot * CAP + t] = e;
}

// ---- char dedupe pass 2: plain store, zero-fills empty slots ----
__global__ void char_slot_sum(const int* __restrict__ counts, const int* __restrict__ evlist,
                              const int* __restrict__ cid, const float* __restrict__ emb,
                              float* __restrict__ h) {
    const int slot = blockIdx.x;
    const int t = threadIdx.x;
    int n = counts[slot];
    if (n > CAP) n = CAP;
    float4 acc = {0.f, 0.f, 0.f, 0.f};
    for (int i = 0; i < n; i++) {
        const int e = evlist[slot * CAP + i];
        const int id = cid[e];
        const float4 v = ((const float4*)(emb + (size_t)id * HD))[t];
        acc.x += v.x; acc.y += v.y; acc.z += v.z; acc.w += v.w;
    }
    ((float4*)(h + (size_t)slot * HD))[t] = acc;
}

// ---- char overflow fallback ----
__global__ void char_overflow(const int* __restrict__ cseq, const int* __restrict__ cpos,
                              const int* __restrict__ cid, const int* __restrict__ ticket,
                              const float* __restrict__ emb, float* __restrict__ h) {
    const int e0 = blockIdx.x * 128;
    const int t = threadIdx.x;
    for (int i = 0; i < 128; i++) {
        const int e = e0 + i;
        if (ticket[e] < CAP) continue;
        const int slot = cseq[e] * ML + cpos[e];
        const int id = cid[e];
        const float4 v = ((const float4*)(emb + (size_t)id * HD))[t];
        float* dst = h + (size_t)slot * HD + t * 4;
        atomicAdd(dst + 0, v.x);
        atomicAdd(dst + 1, v.y);
        atomicAdd(dst + 2, v.z);
        atomicAdd(dst + 3, v.w);
    }
}

// ---- group-event dup detection (all 12 levels at once; indices are static) ----
__global__ void grp_count(const int* __restrict__ iseq, const int* __restrict__ ipos,
                          int* __restrict__ gcounts) {
    const int idx = blockIdx.x * 256 + threadIdx.x;   // 12*16384
    if (idx >= NLEV * NE) return;
    const int lev = idx >> 14;
    atomicAdd(&gcounts[lev * NSLOT + iseq[idx] * ML + ipos[idx]], 1);
}

__global__ void grp_dup(const int* __restrict__ iseq, const int* __restrict__ ipos,
                        const int* __restrict__ gcounts, unsigned char* __restrict__ dup) {
    const int idx = blockIdx.x * 256 + threadIdx.x;
    if (idx >= NLEV * NE) return;
    const int lev = idx >> 14;
    dup[idx] = (gcounts[lev * NSLOT + iseq[idx] * ML + ipos[idx]] > 1) ? 1 : 0;
}

// ---- per-level gather ----
__global__ void gather_x(const float* __restrict__ h, const int* __restrict__ iseq,
                         const int* __restrict__ ifirst, const int* __restrict__ isecond,
                         unsigned short* __restrict__ X) {
    const int e = blockIdx.x;
    const int t = threadIdx.x;
    const int seq = iseq[e], f = ifirst[e], s = isecond[e];
    const float4 a = ((const float4*)(h + ((size_t)seq * ML + f) * HD))[t];
    const float4 b = ((const float4*)(h + ((size_t)seq * ML + s) * HD))[t];
    ushort4 pa, pb;
    pa.x = f2bf(a.x); pa.y = f2bf(a.y); pa.z = f2bf(a.z); pa.w = f2bf(a.w);
    pb.x = f2bf(b.x); pb.y = f2bf(b.y); pb.z = f2bf(b.z); pb.w = f2bf(b.w);
    *(ushort4*)(X + (size_t)e * K2 + t * 4) = pa;
    *(ushort4*)(X + (size_t)e * K2 + HD + t * 4) = pb;
}

// ---- fused GEMM + bias + tanh + dedupe'd scatter ----
// 256M x 128N tile, BK=32, 8 waves (2M x 4N, wave tile 128x32).
// TRIPLE-buffered LDS (3 x 24KB = 72KB) -> 2 independent blocks/CU (4 waves/SIMD):
// one block's barrier/stage stalls hide under the other block's MFMA (m97/m114
// mechanism). One phase + ONE barrier per K-tile. Prefetch distance = 2 K-tiles:
// iter kt reads buf0(tile kt), stages tile kt+2 into buf2 (last read at iter
// kt-1, reads retired before that iter's barrier -> safe). Single vmcnt(3) per
// iter retires tile kt+1 (issued 1 iter ago, consumed next iter => >=2-iter
// issue-to-consume distance for every load, covering L3/HBM latency).
// LDS swizzle (64B rows): phys slot s of row r holds logical chunk s^((r>>1)&3);
// ds_read slot = fq^((fr>>1)&3) -> lanes {fr, fr+8} share a slot = 2-way (free).
__global__ __launch_bounds__(512, 4) void gemm_scatter(
    const unsigned short* __restrict__ X,
    const unsigned short* __restrict__ WbT,
    const float* __restrict__ bias,
    const int* __restrict__ iseq, const int* __restrict__ ipos,
    const unsigned char* __restrict__ dup,
    float* __restrict__ h) {
    extern __shared__ unsigned short lds[];
    const int t = threadIdx.x;
    const int lane = t & 63;
    const int w = t >> 6;            // 0..7
    const int wm = w >> 2;           // 0..1  (M half: 128 rows each)
    const int wn = (w & 3) * 32;     // 0,32,64,96 (N quarter: 32 cols)
    const int fr = lane & 15, fq = lane >> 4;

    // XCD mapping: 512 blocks, 8 XCDs; XCD x owns N-panel x (0.5MB, L2-resident).
    const int bid = blockIdx.x;
    const int col0 = (bid & 7) * 128;
    const int row0 = (bid >> 3) * 256;

    // staging geometry (per K-tile): A = 1024 16B-chunks (2/thread), B = 512 (1/thread).
    // thread t: row = (t>>2) (+128 for A's 2nd chunk), phys pos p = t&3,
    // source chunk = p ^ ((row>>1)&3) = (t&3)^((t>>3)&3)  (same for both A-chunks
    // and B since the +128 / row parity contributions vanish mod 4).
    const int src_c = (t & 3) ^ ((t >> 3) & 3);
    const unsigned short* Asrc = X + (size_t)(row0 + (t >> 2)) * K2 + src_c * 8;
    const unsigned short* Bsrc = WbT + (size_t)(col0 + (t >> 2)) * K2 + src_c * 8;

    f32x4 acc[8][2];
#pragma unroll
    for (int i = 0; i < 8; i++)
#pragma unroll
        for (int j = 0; j < 2; j++) acc[i][j] = (f32x4){0.f, 0.f, 0.f, 0.f};

    unsigned short* b0 = lds;                  // read buffer (tile kt)
    unsigned short* b1 = lds + TILE_ELEMS;     // tile kt+1
    unsigned short* b2 = lds + 2 * TILE_ELEMS; // stage target (tile kt+2)

    // prologue: stage tile0 -> b0, tile1 -> b1
    load_lds_16(Asrc, &b0[t * 8]);
    load_lds_16(Asrc + (size_t)128 * K2, &b0[(512 + t) * 8]);
    load_lds_16(Bsrc, &b0[8192 + t * 8]);
    load_lds_16(Asrc + BK, &b1[t * 8]);
    load_lds_16(Asrc + (size_t)128 * K2 + BK, &b1[(512 + t) * 8]);
    load_lds_16(Bsrc + BK, &b1[8192 + t * 8]);
    asm volatile("s_waitcnt vmcnt(3)" ::: "memory");   // tile0 landed; tile1 in flight
    __builtin_amdgcn_s_barrier();
    asm volatile("" ::: "memory");

    const int slot8 = (fq ^ ((fr >> 1) & 3)) * 8;      // swizzled k-chunk offset (elems)

    for (int kt = 0; kt < NT; kt++) {
        const unsigned short* sA = b0;
        const unsigned short* sB = b0 + 8192;

        bf16x8 af[8], bf[2];
#pragma unroll
        for (int nt = 0; nt < 2; nt++)
            bf[nt] = *(const bf16x8*)&sB[(wn + nt * 16 + fr) * BK + slot8];
#pragma unroll
        for (int mt = 0; mt < 8; mt++)
            af[mt] = *(const bf16x8*)&sA[(wm * 128 + mt * 16 + fr) * BK + slot8];

        if (kt + 2 < NT) {
            const size_t ko = (size_t)(kt + 2) * BK;
            load_lds_16(Asrc + ko, &b2[t * 8]);
            load_lds_16(Asrc + (size_t)128 * K2 + ko, &b2[(512 + t) * 8]);
            load_lds_16(Bsrc + ko, &b2[8192 + t * 8]);
        }

        __builtin_amdgcn_s_setprio(1);
#pragma unroll
        for (int mt = 0; mt < 8; mt++)
#pragma unroll
            for (int nt = 0; nt < 2; nt++)
                acc[mt][nt] = __builtin_amdgcn_mfma_f32_16x16x32_bf16(
                    af[mt], bf[nt], acc[mt][nt], 0, 0, 0);
        __builtin_amdgcn_s_setprio(0);

        if (kt < NT - 2)      { asm volatile("s_waitcnt vmcnt(3)" ::: "memory"); }
        else if (kt == NT - 2){ asm volatile("s_waitcnt vmcnt(0)" ::: "memory"); }
        if (kt < NT - 1) {
            __builtin_amdgcn_s_barrier();
            asm volatile("" ::: "memory");
        }
        // rotate buffers
        unsigned short* tmp = b0; b0 = b1; b1 = b2; b2 = tmp;
    }

    // epilogue: bias + tanh; sole-writer events use plain RMW, dups use atomics
    float bv[2];
#pragma unroll
    for (int ni = 0; ni < 2; ni++) bv[ni] = bias[col0 + wn + ni * 16 + fr];
#pragma unroll
    for (int mi = 0; mi < 8; mi++) {
#pragma unroll
        for (int r = 0; r < 4; r++) {
            const int e = row0 + wm * 128 + mi * 16 + fq * 4 + r;
            const int seq = iseq[e], pos = ipos[e];
            float* hrow = h + ((size_t)seq * ML + pos) * HD + col0 + wn;
            if (dup[e]) {
#pragma unroll
                for (int ni = 0; ni < 2; ni++) {
                    float x = fast_tanh(acc[mi][ni][r] + bv[ni]);
                    atomicAdd(&hrow[ni * 16 + fr], x);
                }
            } else {
#pragma unroll
                for (int ni = 0; ni < 2; ni++) {
                    float x = fast_tanh(acc[mi][ni][r] + bv[ni]);
                    hrow[ni * 16 + fr] += x;
                }
            }
        }
    }
}

// ---- final: h[:, 0, :] = 0 ----
__global__ void zero_first(float* __restrict__ h) {
    const int t = blockIdx.x * 256 + threadIdx.x;
    const int seq = t >> 10, d = t & 1023;
    h[(size_t)seq * ML * HD + d] = 0.0f;
}

extern "C" void kernel_launch(void* const* d_in, const int* in_sizes, int n_in,
                              void* d_out, int out_size, void* d_ws, size_t ws_size,
                              hipStream_t stream) {
    const int* char_i_seq = (const int*)d_in[0];
    const int* char_i_pos = (const int*)d_in[1];
    const int* char_ids   = (const int*)d_in[2];
    const int* grp_i_seq    = (const int*)d_in[3];
    const int* grp_i_first  = (const int*)d_in[4];
    const int* grp_i_second = (const int*)d_in[5];
    const int* grp_i_pos    = (const int*)d_in[6];
    const float* emb = (const float*)d_in[7];
    const float* W   = (const float*)d_in[8];
    const float* b   = (const float*)d_in[9];
    float* h = (float*)d_out;

    unsigned short* WbT = (unsigned short*)d_ws;                            // 4 MB @ 0
    unsigned short* X   = (unsigned short*)((char*)d_ws + (8u << 20));      // 64 MB @ 8M
    int* counts = (int*)((char*)d_ws + (72u << 20));                        // 128 KB
    int* ticket = (int*)((char*)d_ws + (72u << 20) + (1u << 18));           // 128 KB
    int* evlist = (int*)((char*)d_ws + (72u << 20) + (1u << 19));           // 1 MB
    int* gcounts = (int*)((char*)d_ws + (74u << 20));                       // 1.5 MB
    unsigned char* gdup = (unsigned char*)((char*)d_ws + (76u << 20));      // 192 KB

    static bool attr_done = false;
    if (!attr_done) {
        (void)hipFuncSetAttribute((const void*)gemm_scatter,
                                  hipFuncAttributeMaxDynamicSharedMemorySize, LDS_BYTES);
        attr_done = true;
    }

    hipMemsetAsync(counts, 0, NSLOT * sizeof(int), stream);
    hipMemsetAsync(gcounts, 0, (size_t)NLEV * NSLOT * sizeof(int), stream);
    wt_kernel<<<dim3(32, 16), 256, 0, stream>>>(W, WbT);
    char_ticket<<<NEV / 256, 256, 0, stream>>>(char_i_seq, char_i_pos, counts, ticket, evlist);
    char_slot_sum<<<NSLOT, 256, 0, stream>>>(counts, evlist, char_ids, emb, h);
    char_overflow<<<NEV / 128, 256, 0, stream>>>(char_i_seq, char_i_pos, char_ids, ticket, emb, h);
    grp_count<<<(NLEV * NE) / 256, 256, 0, stream>>>(grp_i_seq, grp_i_pos, gcounts);
    grp_dup<<<(NLEV * NE) / 256, 256, 0, stream>>>(grp_i_seq, grp_i_pos, gcounts, gdup);

    for (int lev = 0; lev < NLEV; lev++) {
        const int* iseq = grp_i_seq + lev * NE;
        const int* ifir = grp_i_first + lev * NE;
        const int* isec = grp_i_second + lev * NE;
        const int* ipos = grp_i_pos + lev * NE;
        gather_x<<<NE, 256, 0, stream>>>(h, iseq, ifir, isec, X);
        gemm_scatter<<<dim3(512), 512, LDS_BYTES, stream>>>(X, WbT, b, iseq, ipos,
                                                            gdup + lev * NE, h);
    }
    zero_first<<<32, 256, 0, stream>>>(h);
}

// Round 6
// 1546.924 us; speedup vs baseline: 1.1842x; 1.1842x over previous
//
#include <hip/hip_runtime.h>

#define NS 8
#define ML 4096
#define HD 1024
#define K2 2048
#define NEV 32768
#define NLEV 12
#define NE 16384
#define NSLOT (NS * ML)
#define CAP 8
#define BK 64
#define NT (K2 / BK)          // 32 K-tiles
#define LDS_BYTES 131072      // 2 dbuf x (A 32KB + B 32KB)

typedef __attribute__((ext_vector_type(8))) short bf16x8;
typedef __attribute__((ext_vector_type(4))) float f32x4;

typedef __attribute__((address_space(1))) const void cvoid_g;
typedef __attribute__((address_space(3))) void void_l;

static __device__ __forceinline__ void load_lds_16(const void* g, void* l) {
    __builtin_amdgcn_global_load_lds((cvoid_g*)g, (void_l*)l, 16, 0, 0);
}

static __device__ __forceinline__ unsigned short f2bf(float f) {
    unsigned u = __float_as_uint(f);
    unsigned r = (u + 0x7fffu + ((u >> 16) & 1u)) >> 16;
    return (unsigned short)r;
}

static __device__ __forceinline__ float fast_tanh(float x) {
    return 1.0f - 2.0f / (__expf(2.0f * x) + 1.0f);
}

// ---- W [2048][1024] f32 -> WbT [1024][2048] bf16 (transposed) ----
__global__ void wt_kernel(const float* __restrict__ W, unsigned short* __restrict__ WbT) {
    __shared__ unsigned short tile[64][65];
    const int t = threadIdx.x;
    const int k0 = blockIdx.x * 64;
    const int n0 = blockIdx.y * 64;
#pragma unroll
    for (int i = 0; i < 16; i++) {
        int idx = i * 256 + t;
        int r = idx >> 6, c = idx & 63;
        tile[r][c] = f2bf(W[(size_t)(k0 + r) * HD + n0 + c]);
    }
    __syncthreads();
#pragma unroll
    for (int i = 0; i < 16; i++) {
        int idx = i * 256 + t;
        int r = idx >> 6, c = idx & 63;
        WbT[(size_t)(n0 + r) * K2 + k0 + c] = tile[c][r];
    }
}

// ---- char dedupe pass 1 ----
__global__ void char_ticket(const int* __restrict__ cseq, const int* __restrict__ cpos,
                            int* __restrict__ counts, int* __restrict__ ticket,
                            int* __restrict__ evlist) {
    const int e = blockIdx.x * 256 + threadIdx.x;
    if (e >= NEV) return;
    const int slot = cseq[e] * ML + cpos[e];
    const int t = atomicAdd(&counts[slot], 1);
    ticket[e] = t;
    if (t < CAP) evlist[slot * CAP + t] = e;
}

// ---- char dedupe pass 2: plain store, zero-fills empty slots ----
__global__ void char_slot_sum(const int* __restrict__ counts, const int* __restrict__ evlist,
                              const int* __restrict__ cid, const float* __restrict__ emb,
                              float* __restrict__ h) {
    const int slot = blockIdx.x;
    const int t = threadIdx.x;
    int n = counts[slot];
    if (n > CAP) n = CAP;
    float4 acc = {0.f, 0.f, 0.f, 0.f};
    for (int i = 0; i < n; i++) {
        const int e = evlist[slot * CAP + i];
        const int id = cid[e];
        const float4 v = ((const float4*)(emb + (size_t)id * HD))[t];
        acc.x += v.x; acc.y += v.y; acc.z += v.z; acc.w += v.w;
    }
    ((float4*)(h + (size_t)slot * HD))[t] = acc;
}

// ---- char overflow fallback ----
__global__ void char_overflow(const int* __restrict__ cseq, const int* __restrict__ cpos,
                              const int* __restrict__ cid, const int* __restrict__ ticket,
                              const float* __restrict__ emb, float* __restrict__ h) {
    const int e0 = blockIdx.x * 128;
    const int t = threadIdx.x;
    for (int i = 0; i < 128; i++) {
        const int e = e0 + i;
        if (ticket[e] < CAP) continue;
        const int slot = cseq[e] * ML + cpos[e];
        const int id = cid[e];
        const float4 v = ((const float4*)(emb + (size_t)id * HD))[t];
        float* dst = h + (size_t)slot * HD + t * 4;
        atomicAdd(dst + 0, v.x);
        atomicAdd(dst + 1, v.y);
        atomicAdd(dst + 2, v.z);
        atomicAdd(dst + 3, v.w);
    }
}

// ---- group-event dup detection (all 12 levels at once; indices are static) ----
__global__ void grp_count(const int* __restrict__ iseq, const int* __restrict__ ipos,
                          int* __restrict__ gcounts) {
    const int idx = blockIdx.x * 256 + threadIdx.x;   // 12*16384
    if (idx >= NLEV * NE) return;
    const int lev = idx >> 14;
    atomicAdd(&gcounts[lev * NSLOT + iseq[idx] * ML + ipos[idx]], 1);
}

__global__ void grp_dup(const int* __restrict__ iseq, const int* __restrict__ ipos,
                        const int* __restrict__ gcounts, unsigned char* __restrict__ dup) {
    const int idx = blockIdx.x * 256 + threadIdx.x;
    if (idx >= NLEV * NE) return;
    const int lev = idx >> 14;
    dup[idx] = (gcounts[lev * NSLOT + iseq[idx] * ML + ipos[idx]] > 1) ? 1 : 0;
}

// ---- per-level gather ----
__global__ void gather_x(const float* __restrict__ h, const int* __restrict__ iseq,
                         const int* __restrict__ ifirst, const int* __restrict__ isecond,
                         unsigned short* __restrict__ X) {
    const int e = blockIdx.x;
    const int t = threadIdx.x;
    const int seq = iseq[e], f = ifirst[e], s = isecond[e];
    const float4 a = ((const float4*)(h + ((size_t)seq * ML + f) * HD))[t];
    const float4 b = ((const float4*)(h + ((size_t)seq * ML + s) * HD))[t];
    ushort4 pa, pb;
    pa.x = f2bf(a.x); pa.y = f2bf(a.y); pa.z = f2bf(a.z); pa.w = f2bf(a.w);
    pb.x = f2bf(b.x); pb.y = f2bf(b.y); pb.z = f2bf(b.z); pb.w = f2bf(b.w);
    *(ushort4*)(X + (size_t)e * K2 + t * 4) = pa;
    *(ushort4*)(X + (size_t)e * K2 + HD + t * 4) = pb;
}

// ---- fused GEMM + bias + tanh + dedupe'd scatter ----
// 256x256 tile, BK=64, 8 waves (2M x 4N), 128KB double-buffered LDS.
// Round-6 schedule: EARLY staging + single cheap drain.
//   P1: read af0(8)+bf0(4) | stage A0..A3(kt+1) | bar | MFMA16 | bar
//   P2: read bf1(4)        | stage B0..B3(kt+1) | bar | MFMA16 | bar
//   P3: read af1(8)        |                    | bar | MFMA16 | bar
//   P4:                    |                      MFMA16 | vmcnt(0) | bar
// All 8 stage instrs for tile kt+1 issue in P1/P2 of tile kt; the only wait is
// at P4-end, 2.5-3.5 phases (~2700+ cyc) after issue -> loads have landed, the
// drain is ~free (vs R4's vmcnt(4)/vmcnt(2) with 1-2-phase flight = exposed
// L3/HBM latency twice per K-tile). Buffer safety: dbuf^1 (target) was fully
// read during tile kt-1's phases, all before the barrier into P1(kt).
__global__ __launch_bounds__(512, 2) void gemm_scatter(
    const unsigned short* __restrict__ X,
    const unsigned short* __restrict__ WbT,
    const float* __restrict__ bias,
    const int* __restrict__ iseq, const int* __restrict__ ipos,
    const unsigned char* __restrict__ dup,
    float* __restrict__ h) {
    extern __shared__ unsigned short lds[];
    const int t = threadIdx.x;
    const int lane = t & 63;
    const int w = t >> 6;            // 0..7
    const int wm = w >> 2;           // 0..1  (M half: 128 rows each)
    const int wn = (w & 3) * 64;     // 0,64,128,192 (N quarter: 64 cols)
    const int fr = lane & 15, fq = lane >> 4;

    // bijective XCD swizzle: 256 blocks, 8 XCDs; blocks on one XCD share a B-panel.
    const int bid = blockIdx.x;
    const int xcd = bid & 7, bix = bid >> 3;
    const int row0 = ((xcd & 1) * 32 + bix) * 256;   // 64 row blocks
    const int col0 = (xcd >> 1) * 256;               // 4 col blocks

    // staging geometry: chunk i covers rows i*64..i*64+63; thread t handles
    // row tr = t>>3 within chunk, 16B-position (t&7), xor-swizzled source sp.
    const int tr = t >> 3;
    const int sp = (t & 7) ^ (tr & 7);
    const unsigned short* Asrc = X + (size_t)(row0 + tr) * K2 + sp * 8;
    const unsigned short* Bsrc = WbT + (size_t)(col0 + tr) * K2 + sp * 8;

    f32x4 acc[8][4];
#pragma unroll
    for (int i = 0; i < 8; i++)
#pragma unroll
        for (int j = 0; j < 4; j++) acc[i][j] = (f32x4){0.f, 0.f, 0.f, 0.f};

    // prologue: stage tile 0 -> buf0, full drain
    {
        unsigned short* dA = lds;
        unsigned short* dB = lds + 16384;
#pragma unroll
        for (int i = 0; i < 4; i++)
            load_lds_16(Asrc + (size_t)(i * 64) * K2, &dA[(i * 512 + t) * 8]);
#pragma unroll
        for (int i = 0; i < 4; i++)
            load_lds_16(Bsrc + (size_t)(i * 64) * K2, &dB[(i * 512 + t) * 8]);
        asm volatile("s_waitcnt vmcnt(0)" ::: "memory");
    }
    __builtin_amdgcn_s_barrier();
    asm volatile("" ::: "memory");

    for (int kt = 0; kt < NT; kt++) {
        const int d = kt & 1;
        const unsigned short* sA = lds + d * 32768;
        const unsigned short* sB = sA + 16384;
        unsigned short* nA = lds + (d ^ 1) * 32768;
        unsigned short* nB = nA + 16384;
        const size_t ko = (size_t)(kt + 1) * BK;
        const bool st = (kt + 1 < NT);

        bf16x8 af0[2][4], af1[2][4], bf0[2][2], bf1[2][2];

        // ---------------- P1: af0 + bf0 ; stage A0..A3(kt+1) ----------------
#pragma unroll
        for (int ks = 0; ks < 2; ks++) {
            const int qs = ((ks * 4 + fq) ^ (fr & 7)) * 8;
#pragma unroll
            for (int mt = 0; mt < 4; mt++)
                af0[ks][mt] = *(const bf16x8*)&sA[(wm * 128 + mt * 16 + fr) * BK + qs];
#pragma unroll
            for (int nt = 0; nt < 2; nt++)
                bf0[ks][nt] = *(const bf16x8*)&sB[(wn + nt * 16 + fr) * BK + qs];
        }
        if (st) {
#pragma unroll
            for (int i = 0; i < 4; i++)
                load_lds_16(Asrc + (size_t)(i * 64) * K2 + ko, &nA[(i * 512 + t) * 8]);
        }
        asm volatile("" ::: "memory");
        __builtin_amdgcn_s_barrier();
        asm volatile("" ::: "memory");
        __builtin_amdgcn_s_setprio(1);
#pragma unroll
        for (int ks = 0; ks < 2; ks++)
#pragma unroll
            for (int mt = 0; mt < 4; mt++)
#pragma unroll
                for (int nt = 0; nt < 2; nt++)
                    acc[mt][nt] = __builtin_amdgcn_mfma_f32_16x16x32_bf16(
                        af0[ks][mt], bf0[ks][nt], acc[mt][nt], 0, 0, 0);
        __builtin_amdgcn_s_setprio(0);
        asm volatile("" ::: "memory");
        __builtin_amdgcn_s_barrier();
        asm volatile("" ::: "memory");

        // ---------------- P2: bf1 ; stage B0..B3(kt+1) ----------------
#pragma unroll
        for (int ks = 0; ks < 2; ks++) {
            const int qs = ((ks * 4 + fq) ^ (fr & 7)) * 8;
#pragma unroll
            for (int nt = 0; nt < 2; nt++)
                bf1[ks][nt] = *(const bf16x8*)&sB[(wn + 32 + nt * 16 + fr) * BK + qs];
        }
        if (st) {
#pragma unroll
            for (int i = 0; i < 4; i++)
                load_lds_16(Bsrc + (size_t)(i * 64) * K2 + ko, &nB[(i * 512 + t) * 8]);
        }
        asm volatile("" ::: "memory");
        __builtin_amdgcn_s_barrier();
        asm volatile("" ::: "memory");
        __builtin_amdgcn_s_setprio(1);
#pragma unroll
        for (int ks = 0; ks < 2; ks++)
#pragma unroll
            for (int mt = 0; mt < 4; mt++)
#pragma unroll
                for (int nt = 0; nt < 2; nt++)
                    acc[mt][2 + nt] = __builtin_amdgcn_mfma_f32_16x16x32_bf16(
                        af0[ks][mt], bf1[ks][nt], acc[mt][2 + nt], 0, 0, 0);
        __builtin_amdgcn_s_setprio(0);
        asm volatile("" ::: "memory");
        __builtin_amdgcn_s_barrier();
        asm volatile("" ::: "memory");

        // ---------------- P3: af1 ----------------
#pragma unroll
        for (int ks = 0; ks < 2; ks++) {
            const int qs = ((ks * 4 + fq) ^ (fr & 7)) * 8;
#pragma unroll
            for (int mt = 0; mt < 4; mt++)
                af1[ks][mt] = *(const bf16x8*)&sA[(wm * 128 + 64 + mt * 16 + fr) * BK + qs];
        }
        asm volatile("" ::: "memory");
        __builtin_amdgcn_s_barrier();
        asm volatile("" ::: "memory");
        __builtin_amdgcn_s_setprio(1);
#pragma unroll
        for (int ks = 0; ks < 2; ks++)
#pragma unroll
            for (int mt = 0; mt < 4; mt++)
#pragma unroll
                for (int nt = 0; nt < 2; nt++)
                    acc[4 + mt][nt] = __builtin_amdgcn_mfma_f32_16x16x32_bf16(
                        af1[ks][mt], bf0[ks][nt], acc[4 + mt][nt], 0, 0, 0);
        __builtin_amdgcn_s_setprio(0);
        asm volatile("" ::: "memory");
        __builtin_amdgcn_s_barrier();
        asm volatile("" ::: "memory");

        // ---------------- P4: MFMA ; drain (loads are 2.5-3.5 phases old) ----
        __builtin_amdgcn_s_setprio(1);
#pragma unroll
        for (int ks = 0; ks < 2; ks++)
#pragma unroll
            for (int mt = 0; mt < 4; mt++)
#pragma unroll
                for (int nt = 0; nt < 2; nt++)
                    acc[4 + mt][2 + nt] = __builtin_amdgcn_mfma_f32_16x16x32_bf16(
                        af1[ks][mt], bf1[ks][nt], acc[4 + mt][2 + nt], 0, 0, 0);
        __builtin_amdgcn_s_setprio(0);
        asm volatile("s_waitcnt vmcnt(0)" ::: "memory");
        __builtin_amdgcn_s_barrier();
        asm volatile("" ::: "memory");
    }

    // epilogue: bias + tanh; sole-writer events use plain RMW, dups use atomics
    float bv[4];
#pragma unroll
    for (int ni = 0; ni < 4; ni++) bv[ni] = bias[col0 + wn + ni * 16 + fr];
#pragma unroll
    for (int mi = 0; mi < 8; mi++) {
#pragma unroll
        for (int r = 0; r < 4; r++) {
            const int e = row0 + wm * 128 + mi * 16 + fq * 4 + r;
            const int seq = iseq[e], pos = ipos[e];
            float* hrow = h + ((size_t)seq * ML + pos) * HD + col0 + wn;
            if (dup[e]) {
#pragma unroll
                for (int ni = 0; ni < 4; ni++) {
                    float x = fast_tanh(acc[mi][ni][r] + bv[ni]);
                    atomicAdd(&hrow[ni * 16 + fr], x);
                }
            } else {
#pragma unroll
                for (int ni = 0; ni < 4; ni++) {
                    float x = fast_tanh(acc[mi][ni][r] + bv[ni]);
                    hrow[ni * 16 + fr] += x;
                }
            }
        }
    }
}

// ---- final: h[:, 0, :] = 0 ----
__global__ void zero_first(float* __restrict__ h) {
    const int t = blockIdx.x * 256 + threadIdx.x;
    const int seq = t >> 10, d = t & 1023;
    h[(size_t)seq * ML * HD + d] = 0.0f;
}

extern "C" void kernel_launch(void* const* d_in, const int* in_sizes, int n_in,
                              void* d_out, int out_size, void* d_ws, size_t ws_size,
                              hipStream_t stream) {
    const int* char_i_seq = (const int*)d_in[0];
    const int* char_i_pos = (const int*)d_in[1];
    const int* char_ids   = (const int*)d_in[2];
    const int* grp_i_seq    = (const int*)d_in[3];
    const int* grp_i_first  = (const int*)d_in[4];
    const int* grp_i_second = (const int*)d_in[5];
    const int* grp_i_pos    = (const int*)d_in[6];
    const float* emb = (const float*)d_in[7];
    const float* W   = (const float*)d_in[8];
    const float* b   = (const float*)d_in[9];
    float* h = (float*)d_out;

    unsigned short* WbT = (unsigned short*)d_ws;                            // 4 MB @ 0
    unsigned short* X   = (unsigned short*)((char*)d_ws + (8u << 20));      // 64 MB @ 8M
    int* counts = (int*)((char*)d_ws + (72u << 20));                        // 128 KB
    int* ticket = (int*)((char*)d_ws + (72u << 20) + (1u << 18));           // 128 KB
    int* evlist = (int*)((char*)d_ws + (72u << 20) + (1u << 19));           // 1 MB
    int* gcounts = (int*)((char*)d_ws + (74u << 20));                       // 1.5 MB
    unsigned char* gdup = (unsigned char*)((char*)d_ws + (76u << 20));      // 192 KB

    static bool attr_done = false;
    if (!attr_done) {
        (void)hipFuncSetAttribute((const void*)gemm_scatter,
                                  hipFuncAttributeMaxDynamicSharedMemorySize, LDS_BYTES);
        attr_done = true;
    }

    hipMemsetAsync(counts, 0, NSLOT * sizeof(int), stream);
    hipMemsetAsync(gcounts, 0, (size_t)NLEV * NSLOT * sizeof(int), stream);
    wt_kernel<<<dim3(32, 16), 256, 0, stream>>>(W, WbT);
    char_ticket<<<NEV / 256, 256, 0, stream>>>(char_i_seq, char_i_pos, counts, ticket, evlist);
    char_slot_sum<<<NSLOT, 256, 0, stream>>>(counts, evlist, char_ids, emb, h);
    char_overflow<<<NEV / 128, 256, 0, stream>>>(char_i_seq, char_i_pos, char_ids, ticket, emb, h);
    grp_count<<<(NLEV * NE) / 256, 256, 0, stream>>>(grp_i_seq, grp_i_pos, gcounts);
    grp_dup<<<(NLEV * NE) / 256, 256, 0, stream>>>(grp_i_seq, grp_i_pos, gcounts, gdup);

    for (int lev = 0; lev < NLEV; lev++) {
        const int* iseq = grp_i_seq + lev * NE;
        const int* ifir = grp_i_first + lev * NE;
        const int* isec = grp_i_second + lev * NE;
        const int* ipos = grp_i_pos + lev * NE;
        gather_x<<<NE, 256, 0, stream>>>(h, iseq, ifir, isec, X);
        gemm_scatter<<<dim3(256), 512, LDS_BYTES, stream>>>(X, WbT, b, iseq, ipos,
                                                            gdup + lev * NE, h);
    }
    zero_first<<<32, 256, 0, stream>>>(h);
}

// Round 7
// 1414.729 us; speedup vs baseline: 1.2948x; 1.0934x over previous
//
#include <hip/hip_runtime.h>

#define NS 8
#define ML 4096
#define HD 1024
#define K2 2048
#define NEV 32768
#define NLEV 12
#define NE 16384
#define NSLOT (NS * ML)
#define CAP 8
#define BK 64
#define NT (K2 / BK)          // 32 K-tiles
#define LDS_BYTES 131072      // 2 dbuf x (A 32KB + B 32KB)

typedef __attribute__((ext_vector_type(8))) short bf16x8;
typedef __attribute__((ext_vector_type(4))) float f32x4;

typedef __attribute__((address_space(1))) const void cvoid_g;
typedef __attribute__((address_space(3))) void void_l;

static __device__ __forceinline__ void load_lds_16(const void* g, void* l) {
    __builtin_amdgcn_global_load_lds((cvoid_g*)g, (void_l*)l, 16, 0, 0);
}

static __device__ __forceinline__ unsigned short f2bf(float f) {
    unsigned u = __float_as_uint(f);
    unsigned r = (u + 0x7fffu + ((u >> 16) & 1u)) >> 16;
    return (unsigned short)r;
}

static __device__ __forceinline__ float fast_tanh(float x) {
    return 1.0f - 2.0f / (__expf(2.0f * x) + 1.0f);
}

// ---- W [2048][1024] f32 -> WbT [1024][2048] bf16 (transposed) ----
__global__ void wt_kernel(const float* __restrict__ W, unsigned short* __restrict__ WbT) {
    __shared__ unsigned short tile[64][65];
    const int t = threadIdx.x;
    const int k0 = blockIdx.x * 64;
    const int n0 = blockIdx.y * 64;
#pragma unroll
    for (int i = 0; i < 16; i++) {
        int idx = i * 256 + t;
        int r = idx >> 6, c = idx & 63;
        tile[r][c] = f2bf(W[(size_t)(k0 + r) * HD + n0 + c]);
    }
    __syncthreads();
#pragma unroll
    for (int i = 0; i < 16; i++) {
        int idx = i * 256 + t;
        int r = idx >> 6, c = idx & 63;
        WbT[(size_t)(n0 + r) * K2 + k0 + c] = tile[c][r];
    }
}

// ---- char dedupe pass 1 ----
__global__ void char_ticket(const int* __restrict__ cseq, const int* __restrict__ cpos,
                            int* __restrict__ counts, int* __restrict__ ticket,
                            int* __restrict__ evlist) {
    const int e = blockIdx.x * 256 + threadIdx.x;
    if (e >= NEV) return;
    const int slot = cseq[e] * ML + cpos[e];
    const int t = atomicAdd(&counts[slot], 1);
    ticket[e] = t;
    if (t < CAP) evlist[slot * CAP + t] = e;
}

// ---- char dedupe pass 2: plain store, zero-fills empty slots ----
__global__ void char_slot_sum(const int* __restrict__ counts, const int* __restrict__ evlist,
                              const int* __restrict__ cid, const float* __restrict__ emb,
                              float* __restrict__ h) {
    const int slot = blockIdx.x;
    const int t = threadIdx.x;
    int n = counts[slot];
    if (n > CAP) n = CAP;
    float4 acc = {0.f, 0.f, 0.f, 0.f};
    for (int i = 0; i < n; i++) {
        const int e = evlist[slot * CAP + i];
        const int id = cid[e];
        const float4 v = ((const float4*)(emb + (size_t)id * HD))[t];
        acc.x += v.x; acc.y += v.y; acc.z += v.z; acc.w += v.w;
    }
    ((float4*)(h + (size_t)slot * HD))[t] = acc;
}

// ---- char overflow fallback ----
__global__ void char_overflow(const int* __restrict__ cseq, const int* __restrict__ cpos,
                              const int* __restrict__ cid, const int* __restrict__ ticket,
                              const float* __restrict__ emb, float* __restrict__ h) {
    const int e0 = blockIdx.x * 128;
    const int t = threadIdx.x;
    for (int i = 0; i < 128; i++) {
        const int e = e0 + i;
        if (ticket[e] < CAP) continue;
        const int slot = cseq[e] * ML + cpos[e];
        const int id = cid[e];
        const float4 v = ((const float4*)(emb + (size_t)id * HD))[t];
        float* dst = h + (size_t)slot * HD + t * 4;
        atomicAdd(dst + 0, v.x);
        atomicAdd(dst + 1, v.y);
        atomicAdd(dst + 2, v.z);
        atomicAdd(dst + 3, v.w);
    }
}

// ---- group-event dup detection (all 12 levels at once; indices are static) ----
__global__ void grp_count(const int* __restrict__ iseq, const int* __restrict__ ipos,
                          int* __restrict__ gcounts) {
    const int idx = blockIdx.x * 256 + threadIdx.x;   // 12*16384
    if (idx >= NLEV * NE) return;
    const int lev = idx >> 14;
    atomicAdd(&gcounts[lev * NSLOT + iseq[idx] * ML + ipos[idx]], 1);
}

__global__ void grp_dup(const int* __restrict__ iseq, const int* __restrict__ ipos,
                        const int* __restrict__ gcounts, unsigned char* __restrict__ dup) {
    const int idx = blockIdx.x * 256 + threadIdx.x;
    if (idx >= NLEV * NE) return;
    const int lev = idx >> 14;
    dup[idx] = (gcounts[lev * NSLOT + iseq[idx] * ML + ipos[idx]] > 1) ? 1 : 0;
}

// ---- bf16 shadow of h: full init (after char phase) ----
__global__ void hbf_init(const float* __restrict__ h, unsigned short* __restrict__ hbf) {
    const size_t i = (size_t)blockIdx.x * 256 + threadIdx.x;   // over NSLOT*HD/4
    const float4 v = ((const float4*)h)[i];
    ushort4 p;
    p.x = f2bf(v.x); p.y = f2bf(v.y); p.z = f2bf(v.z); p.w = f2bf(v.w);
    ((ushort4*)hbf)[i] = p;
}

// ---- bf16 shadow: refresh rows touched by this level's scatter ----
// dup rows are written by multiple blocks with IDENTICAL data (benign).
__global__ void hbf_refresh(const float* __restrict__ h, const int* __restrict__ iseq,
                            const int* __restrict__ ipos, unsigned short* __restrict__ hbf) {
    const int e = blockIdx.x;
    const int t = threadIdx.x;
    const size_t row = (size_t)iseq[e] * ML + ipos[e];
    const float4 v = ((const float4*)(h + row * HD))[t];
    ushort4 p;
    p.x = f2bf(v.x); p.y = f2bf(v.y); p.z = f2bf(v.z); p.w = f2bf(v.w);
    ((ushort4*)(hbf + row * HD))[t] = p;
}

// ---- fused GEMM + bias + tanh + dedupe'd scatter ----
// 256x256 tile, BK=64, 8 waves (2M x 4N), 128KB double-buffered LDS.
// R4 4-phase counted-vmcnt schedule, with two round-7 changes:
//  (1) A staged DIRECTLY from the bf16 shadow h_bf via per-thread row-indexed
//      global_load_lds (source addr is per-lane) -> the X intermediate and the
//      gather_x kernel are gone. Snapshot semantics hold: h_bf is frozen during
//      the level (refreshed between kernel launches).
//  (2) every waitcnt+barrier pair is a SINGLE asm blob ("s_waitcnt vmcnt(N);
//      s_barrier") so the compiler has no injection point to add its own
//      vmcnt(0) drain between them.
__global__ __launch_bounds__(512, 2) void gemm_scatter(
    const unsigned short* __restrict__ hbf,
    const unsigned short* __restrict__ WbT,
    const float* __restrict__ bias,
    const int* __restrict__ iseq, const int* __restrict__ ifirst,
    const int* __restrict__ isecond, const int* __restrict__ ipos,
    const unsigned char* __restrict__ dup,
    float* __restrict__ h) {
    extern __shared__ unsigned short lds[];
    const int t = threadIdx.x;
    const int lane = t & 63;
    const int w = t >> 6;            // 0..7
    const int wm = w >> 2;           // 0..1  (M half: 128 rows each)
    const int wn = (w & 3) * 64;     // 0,64,128,192 (N quarter: 64 cols)
    const int fr = lane & 15, fq = lane >> 4;

    // bijective XCD swizzle: 256 blocks, 8 XCDs; blocks on one XCD share a B-panel.
    const int bid = blockIdx.x;
    const int xcd = bid & 7, bix = bid >> 3;
    const int row0 = ((xcd & 1) * 32 + bix) * 256;   // 64 row blocks
    const int col0 = (xcd >> 1) * 256;               // 4 col blocks

    // staging geometry: chunk c covers event rows c*64..c*64+63; thread t handles
    // row tr within chunk, 16B-position (t&7), xor-swizzled source sp.
    // A source = h_bf rows (iseq,ifirst) for k<1024, (iseq,isecond) for k>=1024.
    const int tr = t >> 3;
    const int sp = (t & 7) ^ (tr & 7);
    unsigned offA0[4], offA1[4];                     // elem offsets into hbf
#pragma unroll
    for (int c = 0; c < 4; c++) {
        const int e = row0 + tr + c * 64;
        const int seq = iseq[e];
        offA0[c] = (unsigned)((seq * ML + ifirst[e]) * HD + sp * 8);
        offA1[c] = (unsigned)((seq * ML + isecond[e]) * HD + sp * 8);
    }
    const unsigned short* Bsrc = WbT + (size_t)(col0 + tr) * K2 + sp * 8;

    f32x4 acc[8][4];
#pragma unroll
    for (int i = 0; i < 8; i++)
#pragma unroll
        for (int j = 0; j < 4; j++) acc[i][j] = (f32x4){0.f, 0.f, 0.f, 0.f};

    // prologue: stage tile 0 -> buf0 in steady-state unit order B01,B23,A02,A13
    {
        unsigned short* dA = lds;
        unsigned short* dB = lds + 16384;
        load_lds_16(Bsrc + (size_t)(0 * 64) * K2, &dB[(0 * 512 + t) * 8]);
        load_lds_16(Bsrc + (size_t)(1 * 64) * K2, &dB[(1 * 512 + t) * 8]);
        load_lds_16(Bsrc + (size_t)(2 * 64) * K2, &dB[(2 * 512 + t) * 8]);
        load_lds_16(Bsrc + (size_t)(3 * 64) * K2, &dB[(3 * 512 + t) * 8]);
        load_lds_16(hbf + offA0[0], &dA[(0 * 512 + t) * 8]);
        load_lds_16(hbf + offA0[2], &dA[(2 * 512 + t) * 8]);
        load_lds_16(hbf + offA0[1], &dA[(1 * 512 + t) * 8]);
        load_lds_16(hbf + offA0[3], &dA[(3 * 512 + t) * 8]);
    }
    asm volatile("s_waitcnt vmcnt(2)\n\ts_barrier" ::: "memory");

    for (int kt = 0; kt < NT; kt++) {
        const int d = kt & 1;
        const unsigned short* sA = lds + d * 32768;
        const unsigned short* sB = sA + 16384;
        unsigned short* nA = lds + (d ^ 1) * 32768;
        unsigned short* nB = nA + 16384;
        const size_t ko = (size_t)(kt + 1) * BK;               // B k-offset
        const unsigned koA = (unsigned)(((kt + 1) * BK) & 1023); // A within-row
        const int hsel = (kt + 1) >= (NT / 2);                 // second input half
        const bool st = (kt + 1 < NT);

        bf16x8 af0[2][4], af1[2][4], bf0[2][2], bf1[2][2];

        // ---------------- P1: af0 + bf0 ; stage B01 ----------------
#pragma unroll
        for (int ks = 0; ks < 2; ks++) {
            const int qs = ((ks * 4 + fq) ^ (fr & 7)) * 8;
#pragma unroll
            for (int mt = 0; mt < 4; mt++)
                af0[ks][mt] = *(const bf16x8*)&sA[(wm * 128 + mt * 16 + fr) * BK + qs];
#pragma unroll
            for (int nt = 0; nt < 2; nt++)
                bf0[ks][nt] = *(const bf16x8*)&sB[(wn + nt * 16 + fr) * BK + qs];
        }
        if (st) {
            load_lds_16(Bsrc + (size_t)(0 * 64) * K2 + ko, &nB[(0 * 512 + t) * 8]);
            load_lds_16(Bsrc + (size_t)(1 * 64) * K2 + ko, &nB[(1 * 512 + t) * 8]);
        }
        asm volatile("s_barrier" ::: "memory");
        __builtin_amdgcn_s_setprio(1);
#pragma unroll
        for (int ks = 0; ks < 2; ks++)
#pragma unroll
            for (int mt = 0; mt < 4; mt++)
#pragma unroll
                for (int nt = 0; nt < 2; nt++)
                    acc[mt][nt] = __builtin_amdgcn_mfma_f32_16x16x32_bf16(
                        af0[ks][mt], bf0[ks][nt], acc[mt][nt], 0, 0, 0);
        __builtin_amdgcn_s_setprio(0);
        asm volatile("s_barrier" ::: "memory");

        // ---------------- P2: bf1 ; stage B23 ; vmcnt(4) ----------------
#pragma unroll
        for (int ks = 0; ks < 2; ks++) {
            const int qs = ((ks * 4 + fq) ^ (fr & 7)) * 8;
#pragma unroll
            for (int nt = 0; nt < 2; nt++)
                bf1[ks][nt] = *(const bf16x8*)&sB[(wn + 32 + nt * 16 + fr) * BK + qs];
        }
        if (st) {
            load_lds_16(Bsrc + (size_t)(2 * 64) * K2 + ko, &nB[(2 * 512 + t) * 8]);
            load_lds_16(Bsrc + (size_t)(3 * 64) * K2 + ko, &nB[(3 * 512 + t) * 8]);
        }
        asm volatile("s_barrier" ::: "memory");
        __builtin_amdgcn_s_setprio(1);
#pragma unroll
        for (int ks = 0; ks < 2; ks++)
#pragma unroll
            for (int mt = 0; mt < 4; mt++)
#pragma unroll
                for (int nt = 0; nt < 2; nt++)
                    acc[mt][2 + nt] = __builtin_amdgcn_mfma_f32_16x16x32_bf16(
                        af0[ks][mt], bf1[ks][nt], acc[mt][2 + nt], 0, 0, 0);
        __builtin_amdgcn_s_setprio(0);
        if (st) { asm volatile("s_waitcnt vmcnt(4)\n\ts_barrier" ::: "memory"); }
        else    { asm volatile("s_waitcnt vmcnt(0)\n\ts_barrier" ::: "memory"); }

        // ---------------- P3: af1 ; stage A{0,2} ----------------
#pragma unroll
        for (int ks = 0; ks < 2; ks++) {
            const int qs = ((ks * 4 + fq) ^ (fr & 7)) * 8;
#pragma unroll
            for (int mt = 0; mt < 4; mt++)
                af1[ks][mt] = *(const bf16x8*)&sA[(wm * 128 + 64 + mt * 16 + fr) * BK + qs];
        }
        if (st) {
            const unsigned o0 = (hsel ? offA1[0] : offA0[0]) + koA;
            const unsigned o2 = (hsel ? offA1[2] : offA0[2]) + koA;
            load_lds_16(hbf + o0, &nA[(0 * 512 + t) * 8]);
            load_lds_16(hbf + o2, &nA[(2 * 512 + t) * 8]);
        }
        asm volatile("s_barrier" ::: "memory");
        __builtin_amdgcn_s_setprio(1);
#pragma unroll
        for (int ks = 0; ks < 2; ks++)
#pragma unroll
            for (int mt = 0; mt < 4; mt++)
#pragma unroll
                for (int nt = 0; nt < 2; nt++)
                    acc[4 + mt][nt] = __builtin_amdgcn_mfma_f32_16x16x32_bf16(
                        af1[ks][mt], bf0[ks][nt], acc[4 + mt][nt], 0, 0, 0);
        __builtin_amdgcn_s_setprio(0);
        asm volatile("s_barrier" ::: "memory");

        // ---------------- P4: stage A{1,3} ; MFMA ; vmcnt(2) ----------------
        if (st) {
            const unsigned o1 = (hsel ? offA1[1] : offA0[1]) + koA;
            const unsigned o3 = (hsel ? offA1[3] : offA0[3]) + koA;
            load_lds_16(hbf + o1, &nA[(1 * 512 + t) * 8]);
            load_lds_16(hbf + o3, &nA[(3 * 512 + t) * 8]);
        }
        __builtin_amdgcn_s_setprio(1);
#pragma unroll
        for (int ks = 0; ks < 2; ks++)
#pragma unroll
            for (int mt = 0; mt < 4; mt++)
#pragma unroll
                for (int nt = 0; nt < 2; nt++)
                    acc[4 + mt][2 + nt] = __builtin_amdgcn_mfma_f32_16x16x32_bf16(
                        af1[ks][mt], bf1[ks][nt], acc[4 + mt][2 + nt], 0, 0, 0);
        __builtin_amdgcn_s_setprio(0);
        if (st) { asm volatile("s_waitcnt vmcnt(2)\n\ts_barrier" ::: "memory"); }
        else    { asm volatile("s_waitcnt vmcnt(0)\n\ts_barrier" ::: "memory"); }
    }

    // epilogue: bias + tanh; sole-writer events use plain RMW, dups use atomics
    float bv[4];
#pragma unroll
    for (int ni = 0; ni < 4; ni++) bv[ni] = bias[col0 + wn + ni * 16 + fr];
#pragma unroll
    for (int mi = 0; mi < 8; mi++) {
#pragma unroll
        for (int r = 0; r < 4; r++) {
            const int e = row0 + wm * 128 + mi * 16 + fq * 4 + r;
            const int seq = iseq[e], pos = ipos[e];
            float* hrow = h + ((size_t)seq * ML + pos) * HD + col0 + wn;
            if (dup[e]) {
#pragma unroll
                for (int ni = 0; ni < 4; ni++) {
                    float x = fast_tanh(acc[mi][ni][r] + bv[ni]);
                    atomicAdd(&hrow[ni * 16 + fr], x);
                }
            } else {
#pragma unroll
                for (int ni = 0; ni < 4; ni++) {
                    float x = fast_tanh(acc[mi][ni][r] + bv[ni]);
                    hrow[ni * 16 + fr] += x;
                }
            }
        }
    }
}

// ---- final: h[:, 0, :] = 0 ----
__global__ void zero_first(float* __restrict__ h) {
    const int t = blockIdx.x * 256 + threadIdx.x;
    const int seq = t >> 10, d = t & 1023;
    h[(size_t)seq * ML * HD + d] = 0.0f;
}

extern "C" void kernel_launch(void* const* d_in, const int* in_sizes, int n_in,
                              void* d_out, int out_size, void* d_ws, size_t ws_size,
                              hipStream_t stream) {
    const int* char_i_seq = (const int*)d_in[0];
    const int* char_i_pos = (const int*)d_in[1];
    const int* char_ids   = (const int*)d_in[2];
    const int* grp_i_seq    = (const int*)d_in[3];
    const int* grp_i_first  = (const int*)d_in[4];
    const int* grp_i_second = (const int*)d_in[5];
    const int* grp_i_pos    = (const int*)d_in[6];
    const float* emb = (const float*)d_in[7];
    const float* W   = (const float*)d_in[8];
    const float* b   = (const float*)d_in[9];
    float* h = (float*)d_out;

    unsigned short* WbT = (unsigned short*)d_ws;                            // 4 MB @ 0
    unsigned short* hbf = (unsigned short*)((char*)d_ws + (8u << 20));      // 64 MB @ 8M
    int* counts = (int*)((char*)d_ws + (72u << 20));                        // 128 KB
    int* ticket = (int*)((char*)d_ws + (72u << 20) + (1u << 18));           // 128 KB
    int* evlist = (int*)((char*)d_ws + (72u << 20) + (1u << 19));           // 1 MB
    int* gcounts = (int*)((char*)d_ws + (74u << 20));                       // 1.5 MB
    unsigned char* gdup = (unsigned char*)((char*)d_ws + (76u << 20));      // 192 KB

    static bool attr_done = false;
    if (!attr_done) {
        (void)hipFuncSetAttribute((const void*)gemm_scatter,
                                  hipFuncAttributeMaxDynamicSharedMemorySize, LDS_BYTES);
        attr_done = true;
    }

    hipMemsetAsync(counts, 0, NSLOT * sizeof(int), stream);
    hipMemsetAsync(gcounts, 0, (size_t)NLEV * NSLOT * sizeof(int), stream);
    wt_kernel<<<dim3(32, 16), 256, 0, stream>>>(W, WbT);
    char_ticket<<<NEV / 256, 256, 0, stream>>>(char_i_seq, char_i_pos, counts, ticket, evlist);
    char_slot_sum<<<NSLOT, 256, 0, stream>>>(counts, evlist, char_ids, emb, h);
    char_overflow<<<NEV / 128, 256, 0, stream>>>(char_i_seq, char_i_pos, char_ids, ticket, emb, h);
    grp_count<<<(NLEV * NE) / 256, 256, 0, stream>>>(grp_i_seq, grp_i_pos, gcounts);
    grp_dup<<<(NLEV * NE) / 256, 256, 0, stream>>>(grp_i_seq, grp_i_pos, gcounts, gdup);
    hbf_init<<<NSLOT, 256, 0, stream>>>(h, hbf);   // NSLOT*HD/4 elems / 256 thr = NSLOT blocks

    for (int lev = 0; lev < NLEV; lev++) {
        const int* iseq = grp_i_seq + lev * NE;
        const int* ifir = grp_i_first + lev * NE;
        const int* isec = grp_i_second + lev * NE;
        const int* ipos = grp_i_pos + lev * NE;
        gemm_scatter<<<dim3(256), 512, LDS_BYTES, stream>>>(hbf, WbT, b, iseq, ifir, isec,
                                                            ipos, gdup + lev * NE, h);
        if (lev + 1 < NLEV)
            hbf_refresh<<<NE, 256, 0, stream>>>(h, iseq, ipos, hbf);
    }
    zero_first<<<32, 256, 0, stream>>>(h);
}

// Round 8
// 1399.956 us; speedup vs baseline: 1.3085x; 1.0106x over previous
//
#include <hip/hip_runtime.h>

#define NS 8
#define ML 4096
#define HD 1024
#define K2 2048
#define NEV 32768
#define NLEV 12
#define NE 16384
#define NSLOT (NS * ML)
#define CAP 8
#define BK 64
#define NT (K2 / BK)          // 32 K-tiles
#define LDS_BYTES 131072      // 2 dbuf x (A 32KB + B 32KB)

typedef __attribute__((ext_vector_type(8))) short bf16x8;
typedef __attribute__((ext_vector_type(4))) float f32x4;

typedef __attribute__((address_space(1))) const void cvoid_g;
typedef __attribute__((address_space(3))) void void_l;

static __device__ __forceinline__ void load_lds_16(const void* g, void* l) {
    __builtin_amdgcn_global_load_lds((cvoid_g*)g, (void_l*)l, 16, 0, 0);
}

static __device__ __forceinline__ unsigned short f2bf(float f) {
    unsigned u = __float_as_uint(f);
    unsigned r = (u + 0x7fffu + ((u >> 16) & 1u)) >> 16;
    return (unsigned short)r;
}

static __device__ __forceinline__ float fast_tanh(float x) {
    return 1.0f - 2.0f / (__expf(2.0f * x) + 1.0f);
}

// ---- W [2048][1024] f32 -> WbT [1024][2048] bf16 (transposed) ----
__global__ void wt_kernel(const float* __restrict__ W, unsigned short* __restrict__ WbT) {
    __shared__ unsigned short tile[64][65];
    const int t = threadIdx.x;
    const int k0 = blockIdx.x * 64;
    const int n0 = blockIdx.y * 64;
#pragma unroll
    for (int i = 0; i < 16; i++) {
        int idx = i * 256 + t;
        int r = idx >> 6, c = idx & 63;
        tile[r][c] = f2bf(W[(size_t)(k0 + r) * HD + n0 + c]);
    }
    __syncthreads();
#pragma unroll
    for (int i = 0; i < 16; i++) {
        int idx = i * 256 + t;
        int r = idx >> 6, c = idx & 63;
        WbT[(size_t)(n0 + r) * K2 + k0 + c] = tile[c][r];
    }
}

// ---- char dedupe pass 1 ----
__global__ void char_ticket(const int* __restrict__ cseq, const int* __restrict__ cpos,
                            int* __restrict__ counts, int* __restrict__ ticket,
                            int* __restrict__ evlist) {
    const int e = blockIdx.x * 256 + threadIdx.x;
    if (e >= NEV) return;
    const int slot = cseq[e] * ML + cpos[e];
    const int t = atomicAdd(&counts[slot], 1);
    ticket[e] = t;
    if (t < CAP) evlist[slot * CAP + t] = e;
}

// ---- char dedupe pass 2: plain store, zero-fills empty slots ----
__global__ void char_slot_sum(const int* __restrict__ counts, const int* __restrict__ evlist,
                              const int* __restrict__ cid, const float* __restrict__ emb,
                              float* __restrict__ h) {
    const int slot = blockIdx.x;
    const int t = threadIdx.x;
    int n = counts[slot];
    if (n > CAP) n = CAP;
    float4 acc = {0.f, 0.f, 0.f, 0.f};
    for (int i = 0; i < n; i++) {
        const int e = evlist[slot * CAP + i];
        const int id = cid[e];
        const float4 v = ((const float4*)(emb + (size_t)id * HD))[t];
        acc.x += v.x; acc.y += v.y; acc.z += v.z; acc.w += v.w;
    }
    ((float4*)(h + (size_t)slot * HD))[t] = acc;
}

// ---- char overflow fallback ----
__global__ void char_overflow(const int* __restrict__ cseq, const int* __restrict__ cpos,
                              const int* __restrict__ cid, const int* __restrict__ ticket,
                              const float* __restrict__ emb, float* __restrict__ h) {
    const int e0 = blockIdx.x * 128;
    const int t = threadIdx.x;
    for (int i = 0; i < 128; i++) {
        const int e = e0 + i;
        if (ticket[e] < CAP) continue;
        const int slot = cseq[e] * ML + cpos[e];
        const int id = cid[e];
        const float4 v = ((const float4*)(emb + (size_t)id * HD))[t];
        float* dst = h + (size_t)slot * HD + t * 4;
        atomicAdd(dst + 0, v.x);
        atomicAdd(dst + 1, v.y);
        atomicAdd(dst + 2, v.z);
        atomicAdd(dst + 3, v.w);
    }
}

// ---- group-event dup detection (all 12 levels at once; indices are static) ----
__global__ void grp_count(const int* __restrict__ iseq, const int* __restrict__ ipos,
                          int* __restrict__ gcounts) {
    const int idx = blockIdx.x * 256 + threadIdx.x;   // 12*16384
    if (idx >= NLEV * NE) return;
    const int lev = idx >> 14;
    atomicAdd(&gcounts[lev * NSLOT + iseq[idx] * ML + ipos[idx]], 1);
}

__global__ void grp_dup(const int* __restrict__ iseq, const int* __restrict__ ipos,
                        const int* __restrict__ gcounts, unsigned char* __restrict__ dup) {
    const int idx = blockIdx.x * 256 + threadIdx.x;
    if (idx >= NLEV * NE) return;
    const int lev = idx >> 14;
    dup[idx] = (gcounts[lev * NSLOT + iseq[idx] * ML + ipos[idx]] > 1) ? 1 : 0;
}

// ---- bf16 shadow of h: full init (after char phase) ----
__global__ void hbf_init(const float* __restrict__ h, unsigned short* __restrict__ hbf) {
    const size_t i = (size_t)blockIdx.x * 256 + threadIdx.x;   // over NSLOT*HD/4
    const float4 v = ((const float4*)h)[i];
    ushort4 p;
    p.x = f2bf(v.x); p.y = f2bf(v.y); p.z = f2bf(v.z); p.w = f2bf(v.w);
    ((ushort4*)hbf)[i] = p;
}

// ---- bf16 shadow: refresh rows touched by this level's scatter ----
// dup rows are written by multiple blocks with IDENTICAL data (benign).
__global__ void hbf_refresh(const float* __restrict__ h, const int* __restrict__ iseq,
                            const int* __restrict__ ipos, unsigned short* __restrict__ hbf) {
    const int e = blockIdx.x;
    const int t = threadIdx.x;
    const size_t row = (size_t)iseq[e] * ML + ipos[e];
    const float4 v = ((const float4*)(h + row * HD))[t];
    ushort4 p;
    p.x = f2bf(v.x); p.y = f2bf(v.y); p.z = f2bf(v.z); p.w = f2bf(v.w);
    ((ushort4*)(hbf + row * HD))[t] = p;
}

// ---- fused GEMM + bias + tanh + dedupe'd scatter ----
// 256x256 tile, BK=64, 8 waves (2M x 4N), 128KB double-buffered LDS.
// Round-8: FRAGMENT READ-AHEAD pipeline (the m201 mechanism, correctly ported).
// Per K-tile, ONE barrier; ds_reads issued in phase p are consumed in phase p+1,
// so the LDS unit works DURING the MFMA phases (max(LDS,MFMA) per tile, not sum):
//   P1: stage A(kt+1)->nxt | read bf1(cur)  | MFMA q1 (af0 x bf0)   [read last P4]
//   P2: stage B(kt+1)->nxt | read af1(cur)  | MFMA q2 (af0 x bf1)
//   P3:                                       MFMA q3 (af1 x bf0)
//   P4: vmcnt(0)+s_barrier | read af0,bf0 of kt+1 from nxt | MFMA q4 (af1 x bf1)
// Safety: every read of buffer d is lgkm-drained by its consuming MFMA before
// the wave reaches the P4 barrier; post-barrier reads touch only nxt; next-iter
// stages write only old-d. Compiler emits COUNTED lgkm waits (no syncthreads).
__global__ __launch_bounds__(512, 2) void gemm_scatter(
    const unsigned short* __restrict__ hbf,
    const unsigned short* __restrict__ WbT,
    const float* __restrict__ bias,
    const int* __restrict__ iseq, const int* __restrict__ ifirst,
    const int* __restrict__ isecond, const int* __restrict__ ipos,
    const unsigned char* __restrict__ dup,
    float* __restrict__ h) {
    extern __shared__ unsigned short lds[];
    const int t = threadIdx.x;
    const int lane = t & 63;
    const int w = t >> 6;            // 0..7
    const int wm = w >> 2;           // 0..1  (M half: 128 rows each)
    const int wn = (w & 3) * 64;     // 0,64,128,192 (N quarter: 64 cols)
    const int fr = lane & 15, fq = lane >> 4;

    // bijective XCD swizzle: 256 blocks, 8 XCDs; blocks on one XCD share a B-panel.
    const int bid = blockIdx.x;
    const int xcd = bid & 7, bix = bid >> 3;
    const int row0 = ((xcd & 1) * 32 + bix) * 256;   // 64 row blocks
    const int col0 = (xcd >> 1) * 256;               // 4 col blocks

    // staging geometry: chunk c covers event rows c*64..c*64+63; thread t handles
    // row tr within chunk, 16B-position (t&7), xor-swizzled source sp.
    // A source = h_bf rows (iseq,ifirst) for k<1024, (iseq,isecond) for k>=1024.
    const int tr = t >> 3;
    const int sp = (t & 7) ^ (tr & 7);
    unsigned offA0[4], offA1[4];                     // elem offsets into hbf
#pragma unroll
    for (int c = 0; c < 4; c++) {
        const int e = row0 + tr + c * 64;
        const int seq = iseq[e];
        offA0[c] = (unsigned)((seq * ML + ifirst[e]) * HD + sp * 8);
        offA1[c] = (unsigned)((seq * ML + isecond[e]) * HD + sp * 8);
    }
    const unsigned short* Bsrc = WbT + (size_t)(col0 + tr) * K2 + sp * 8;

    f32x4 acc[8][4];
#pragma unroll
    for (int i = 0; i < 8; i++)
#pragma unroll
        for (int j = 0; j < 4; j++) acc[i][j] = (f32x4){0.f, 0.f, 0.f, 0.f};

    // prologue: stage tile 0 -> buf0, drain, then read-ahead q1 operands
    {
        unsigned short* dA = lds;
        unsigned short* dB = lds + 16384;
        load_lds_16(hbf + offA0[0], &dA[(0 * 512 + t) * 8]);
        load_lds_16(hbf + offA0[1], &dA[(1 * 512 + t) * 8]);
        load_lds_16(hbf + offA0[2], &dA[(2 * 512 + t) * 8]);
        load_lds_16(hbf + offA0[3], &dA[(3 * 512 + t) * 8]);
        load_lds_16(Bsrc + (size_t)(0 * 64) * K2, &dB[(0 * 512 + t) * 8]);
        load_lds_16(Bsrc + (size_t)(1 * 64) * K2, &dB[(1 * 512 + t) * 8]);
        load_lds_16(Bsrc + (size_t)(2 * 64) * K2, &dB[(2 * 512 + t) * 8]);
        load_lds_16(Bsrc + (size_t)(3 * 64) * K2, &dB[(3 * 512 + t) * 8]);
    }
    asm volatile("s_waitcnt vmcnt(0)\n\ts_barrier" ::: "memory");

    bf16x8 af0[2][4], af1[2][4], bf0[2][2], bf1[2][2];
    {
        const unsigned short* sA = lds;
        const unsigned short* sB = lds + 16384;
#pragma unroll
        for (int ks = 0; ks < 2; ks++) {
            const int qs = ((ks * 4 + fq) ^ (fr & 7)) * 8;
#pragma unroll
            for (int mt = 0; mt < 4; mt++)
                af0[ks][mt] = *(const bf16x8*)&sA[(wm * 128 + mt * 16 + fr) * BK + qs];
#pragma unroll
            for (int nt = 0; nt < 2; nt++)
                bf0[ks][nt] = *(const bf16x8*)&sB[(wn + nt * 16 + fr) * BK + qs];
        }
    }

    for (int kt = 0; kt < NT; kt++) {
        const int d = kt & 1;
        const unsigned short* sA = lds + d * 32768;
        const unsigned short* sB = sA + 16384;
        unsigned short* nA = lds + (d ^ 1) * 32768;
        unsigned short* nB = nA + 16384;
        const size_t ko = (size_t)(kt + 1) * BK;                 // B k-offset
        const unsigned koA = (unsigned)(((kt + 1) * BK) & 1023); // A within-row
        const int hsel = (kt + 1) >= (NT / 2);                   // second input half
        const bool st = (kt + 1 < NT);

        // ---- P1: stage A(kt+1) ; read bf1 ; MFMA q1 ----
        if (st) {
            const unsigned o0 = (hsel ? offA1[0] : offA0[0]) + koA;
            const unsigned o1 = (hsel ? offA1[1] : offA0[1]) + koA;
            const unsigned o2 = (hsel ? offA1[2] : offA0[2]) + koA;
            const unsigned o3 = (hsel ? offA1[3] : offA0[3]) + koA;
            load_lds_16(hbf + o0, &nA[(0 * 512 + t) * 8]);
            load_lds_16(hbf + o1, &nA[(1 * 512 + t) * 8]);
            load_lds_16(hbf + o2, &nA[(2 * 512 + t) * 8]);
            load_lds_16(hbf + o3, &nA[(3 * 512 + t) * 8]);
        }
#pragma unroll
        for (int ks = 0; ks < 2; ks++) {
            const int qs = ((ks * 4 + fq) ^ (fr & 7)) * 8;
#pragma unroll
            for (int nt = 0; nt < 2; nt++)
                bf1[ks][nt] = *(const bf16x8*)&sB[(wn + 32 + nt * 16 + fr) * BK + qs];
        }
        __builtin_amdgcn_s_setprio(1);
#pragma unroll
        for (int ks = 0; ks < 2; ks++)
#pragma unroll
            for (int mt = 0; mt < 4; mt++)
#pragma unroll
                for (int nt = 0; nt < 2; nt++)
                    acc[mt][nt] = __builtin_amdgcn_mfma_f32_16x16x32_bf16(
                        af0[ks][mt], bf0[ks][nt], acc[mt][nt], 0, 0, 0);
        __builtin_amdgcn_s_setprio(0);

        // ---- P2: stage B(kt+1) ; read af1 ; MFMA q2 ----
        if (st) {
            load_lds_16(Bsrc + (size_t)(0 * 64) * K2 + ko, &nB[(0 * 512 + t) * 8]);
            load_lds_16(Bsrc + (size_t)(1 * 64) * K2 + ko, &nB[(1 * 512 + t) * 8]);
            load_lds_16(Bsrc + (size_t)(2 * 64) * K2 + ko, &nB[(2 * 512 + t) * 8]);
            load_lds_16(Bsrc + (size_t)(3 * 64) * K2 + ko, &nB[(3 * 512 + t) * 8]);
        }
#pragma unroll
        for (int ks = 0; ks < 2; ks++) {
            const int qs = ((ks * 4 + fq) ^ (fr & 7)) * 8;
#pragma unroll
            for (int mt = 0; mt < 4; mt++)
                af1[ks][mt] = *(const bf16x8*)&sA[(wm * 128 + 64 + mt * 16 + fr) * BK + qs];
        }
        __builtin_amdgcn_s_setprio(1);
#pragma unroll
        for (int ks = 0; ks < 2; ks++)
#pragma unroll
            for (int mt = 0; mt < 4; mt++)
#pragma unroll
                for (int nt = 0; nt < 2; nt++)
                    acc[mt][2 + nt] = __builtin_amdgcn_mfma_f32_16x16x32_bf16(
                        af0[ks][mt], bf1[ks][nt], acc[mt][2 + nt], 0, 0, 0);
        __builtin_amdgcn_s_setprio(0);

        // ---- P3: MFMA q3 ----
        __builtin_amdgcn_s_setprio(1);
#pragma unroll
        for (int ks = 0; ks < 2; ks++)
#pragma unroll
            for (int mt = 0; mt < 4; mt++)
#pragma unroll
                for (int nt = 0; nt < 2; nt++)
                    acc[4 + mt][nt] = __builtin_amdgcn_mfma_f32_16x16x32_bf16(
                        af1[ks][mt], bf0[ks][nt], acc[4 + mt][nt], 0, 0, 0);
        __builtin_amdgcn_s_setprio(0);

        // ---- P4: sync ; read-ahead q1(kt+1) ; MFMA q4 ----
        if (st) {
            asm volatile("s_waitcnt vmcnt(0)\n\ts_barrier" ::: "memory");
#pragma unroll
            for (int ks = 0; ks < 2; ks++) {
                const int qs = ((ks * 4 + fq) ^ (fr & 7)) * 8;
#pragma unroll
                for (int mt = 0; mt < 4; mt++)
                    af0[ks][mt] = *(const bf16x8*)&nA[(wm * 128 + mt * 16 + fr) * BK + qs];
#pragma unroll
                for (int nt = 0; nt < 2; nt++)
                    bf0[ks][nt] = *(const bf16x8*)&nB[(wn + nt * 16 + fr) * BK + qs];
            }
        }
        __builtin_amdgcn_s_setprio(1);
#pragma unroll
        for (int ks = 0; ks < 2; ks++)
#pragma unroll
            for (int mt = 0; mt < 4; mt++)
#pragma unroll
                for (int nt = 0; nt < 2; nt++)
                    acc[4 + mt][2 + nt] = __builtin_amdgcn_mfma_f32_16x16x32_bf16(
                        af1[ks][mt], bf1[ks][nt], acc[4 + mt][2 + nt], 0, 0, 0);
        __builtin_amdgcn_s_setprio(0);
    }

    // epilogue: bias + tanh; sole-writer events use plain RMW, dups use atomics
    float bv[4];
#pragma unroll
    for (int ni = 0; ni < 4; ni++) bv[ni] = bias[col0 + wn + ni * 16 + fr];
#pragma unroll
    for (int mi = 0; mi < 8; mi++) {
#pragma unroll
        for (int r = 0; r < 4; r++) {
            const int e = row0 + wm * 128 + mi * 16 + fq * 4 + r;
            const int seq = iseq[e], pos = ipos[e];
            float* hrow = h + ((size_t)seq * ML + pos) * HD + col0 + wn;
            if (dup[e]) {
#pragma unroll
                for (int ni = 0; ni < 4; ni++) {
                    float x = fast_tanh(acc[mi][ni][r] + bv[ni]);
                    atomicAdd(&hrow[ni * 16 + fr], x);
                }
            } else {
#pragma unroll
                for (int ni = 0; ni < 4; ni++) {
                    float x = fast_tanh(acc[mi][ni][r] + bv[ni]);
                    hrow[ni * 16 + fr] += x;
                }
            }
        }
    }
}

// ---- final: h[:, 0, :] = 0 ----
__global__ void zero_first(float* __restrict__ h) {
    const int t = blockIdx.x * 256 + threadIdx.x;
    const int seq = t >> 10, d = t & 1023;
    h[(size_t)seq * ML * HD + d] = 0.0f;
}

extern "C" void kernel_launch(void* const* d_in, const int* in_sizes, int n_in,
                              void* d_out, int out_size, void* d_ws, size_t ws_size,
                              hipStream_t stream) {
    const int* char_i_seq = (const int*)d_in[0];
    const int* char_i_pos = (const int*)d_in[1];
    const int* char_ids   = (const int*)d_in[2];
    const int* grp_i_seq    = (const int*)d_in[3];
    const int* grp_i_first  = (const int*)d_in[4];
    const int* grp_i_second = (const int*)d_in[5];
    const int* grp_i_pos    = (const int*)d_in[6];
    const float* emb = (const float*)d_in[7];
    const float* W   = (const float*)d_in[8];
    const float* b   = (const float*)d_in[9];
    float* h = (float*)d_out;

    unsigned short* WbT = (unsigned short*)d_ws;                            // 4 MB @ 0
    unsigned short* hbf = (unsigned short*)((char*)d_ws + (8u << 20));      // 64 MB @ 8M
    int* counts = (int*)((char*)d_ws + (72u << 20));                        // 128 KB
    int* ticket = (int*)((char*)d_ws + (72u << 20) + (1u << 18));           // 128 KB
    int* evlist = (int*)((char*)d_ws + (72u << 20) + (1u << 19));           // 1 MB
    int* gcounts = (int*)((char*)d_ws + (74u << 20));                       // 1.5 MB
    unsigned char* gdup = (unsigned char*)((char*)d_ws + (76u << 20));      // 192 KB

    static bool attr_done = false;
    if (!attr_done) {
        (void)hipFuncSetAttribute((const void*)gemm_scatter,
                                  hipFuncAttributeMaxDynamicSharedMemorySize, LDS_BYTES);
        attr_done = true;
    }

    hipMemsetAsync(counts, 0, NSLOT * sizeof(int), stream);
    hipMemsetAsync(gcounts, 0, (size_t)NLEV * NSLOT * sizeof(int), stream);
    wt_kernel<<<dim3(32, 16), 256, 0, stream>>>(W, WbT);
    char_ticket<<<NEV / 256, 256, 0, stream>>>(char_i_seq, char_i_pos, counts, ticket, evlist);
    char_slot_sum<<<NSLOT, 256, 0, stream>>>(counts, evlist, char_ids, emb, h);
    char_overflow<<<NEV / 128, 256, 0, stream>>>(char_i_seq, char_i_pos, char_ids, ticket, emb, h);
    grp_count<<<(NLEV * NE) / 256, 256, 0, stream>>>(grp_i_seq, grp_i_pos, gcounts);
    grp_dup<<<(NLEV * NE) / 256, 256, 0, stream>>>(grp_i_seq, grp_i_pos, gcounts, gdup);
    hbf_init<<<NSLOT, 256, 0, stream>>>(h, hbf);   // NSLOT*HD/4 elems / 256 thr = NSLOT blocks

    for (int lev = 0; lev < NLEV; lev++) {
        const int* iseq = grp_i_seq + lev * NE;
        const int* ifir = grp_i_first + lev * NE;
        const int* isec = grp_i_second + lev * NE;
        const int* ipos = grp_i_pos + lev * NE;
        gemm_scatter<<<dim3(256), 512, LDS_BYTES, stream>>>(hbf, WbT, b, iseq, ifir, isec,
                                                            ipos, gdup + lev * NE, h);
        if (lev + 1 < NLEV)
            hbf_refresh<<<NE, 256, 0, stream>>>(h, iseq, ipos, hbf);
    }
    zero_first<<<32, 256, 0, stream>>>(h);
}